// Round 5
// baseline (296.077 us; speedup 1.0000x reference)
//
#include <hip/hip_runtime.h>
#include <stdint.h>

typedef __bf16 bf16x8 __attribute__((ext_vector_type(8)));
typedef float f32x4 __attribute__((ext_vector_type(4)));

static constexpr float QK_SCALE = 0.044194173824159216f; // 1/sqrt(512)

__device__ __forceinline__ uint16_t f2bf(float f) {
    uint32_t x = __builtin_bit_cast(uint32_t, f);
    x += 0x7FFFu + ((x >> 16) & 1u);     // round-to-nearest-even; inputs finite
    return (uint16_t)(x >> 16);
}

// async 16B global->LDS copy (global_load_lds_dwordx4). LDS dest is
// wave-uniform base + lane*16; lds ptr = region_base + lane*16 matches.
__device__ __forceinline__ void cp16(const uint16_t* g, uint16_t* l) {
    __builtin_amdgcn_global_load_lds(
        (__attribute__((address_space(1))) void*)(uint16_t*)g,
        (__attribute__((address_space(3))) void*)l,
        16, 0, 0);
}

// ---------------------------------------------------------------------------
// NT GEMM: C[M,N] = A[M,K] * B[N,K]^T  (both K-contiguous, bf16)
// 128x128 block tile, BK=32, 256 thr = 4 waves (2x2), 64x64/wave.
// 3-stage circular LDS pipeline (48 KB) -> 3 blocks/CU. One guard per iter:
// vmcnt(4)+lgkmcnt(0)+s_barrier (stage k landed; k+1,k+2 stay in flight).
// XOR-swizzled 16B chunks (0 bank conflicts, verified). XCD supertile
// swizzle. MFMA operands swapped -> C^T layout -> packed stores.
// Only MODE 3 instantiated now (QKV split epilogue: Q | K | V transposed).
// ---------------------------------------------------------------------------
template <int MODE>
__global__ __launch_bounds__(256, 3) void gemm_nt(
    const uint16_t* __restrict__ A, const uint16_t* __restrict__ Bm,
    void* __restrict__ C0, void* __restrict__ C1, void* __restrict__ C2,
    const float* __restrict__ bias0, const float* __restrict__ bias1,
    const float* __restrict__ bias2,
    float scale, int K, int ldc, long bsA, long bsB, long bsC,
    int scols, int stPerBatch)
{
    __shared__ __align__(16) uint16_t SH[3][8192];

    const uint32_t id  = blockIdx.x;
    const uint32_t xcd = id & 7u;
    const uint32_t p   = id >> 3;
    const uint32_t q   = p >> 4;
    const uint32_t w   = p & 15u;
    const uint32_t g   = q * 8u + xcd;
    const uint32_t bz  = g / (uint32_t)stPerBatch;
    const uint32_t gs  = g - bz * (uint32_t)stPerBatch;
    const uint32_t sr  = gs / (uint32_t)scols;
    const uint32_t sc  = gs - sr * (uint32_t)scols;
    const int bm = (int)(sr * 4u + (w >> 2));
    const int bn = (int)(sc * 4u + (w & 3u));

    const int t  = threadIdx.x;
    const int wave = t >> 6, lane = t & 63;
    const int wm = (wave >> 1) * 64, wn = (wave & 1) * 64;
    const int lm = lane & 15, lq = lane >> 4;
    const int sw = lq ^ ((lm >> 1) & 3);          // read-side swizzled k-group

    const uint16_t* Ab = A  + (long)bz * bsA + (long)bm * 128 * K;
    const uint16_t* Bb = Bm + (long)bz * bsB + (long)bn * 128 * K;

    long goff[2]; int loff[2];
#pragma unroll
    for (int j = 0; j < 2; ++j) {
        const int s  = j * 256 + t;
        const int r  = s >> 2;
        const int cs = s & 3;
        const int cg = cs ^ ((r >> 1) & 3);
        goff[j] = (long)r * K + cg * 8;
        loff[j] = s * 8;
    }

    const int KI = K >> 5;

#pragma unroll
    for (int st = 0; st < 2; ++st)
#pragma unroll
        for (int j = 0; j < 2; ++j) {
            cp16(Ab + goff[j] + st * 32, SH[st] + loff[j]);
            cp16(Bb + goff[j] + st * 32, SH[st] + 4096 + loff[j]);
        }

    f32x4 acc[4][4] = {};

    int cur = 0, pf = 2;
    for (int k = 0; k < KI; ++k) {
        asm volatile("s_waitcnt vmcnt(4) lgkmcnt(0)\n\ts_barrier" ::: "memory");

        int kp = k + 2; if (kp >= KI) kp = KI - 1;
        uint16_t* dst = SH[pf];
        const long ko = (long)kp * 32;
#pragma unroll
        for (int j = 0; j < 2; ++j) {
            cp16(Ab + goff[j] + ko, dst + loff[j]);
            cp16(Bb + goff[j] + ko, dst + 4096 + loff[j]);
        }

        const uint16_t* buf = SH[cur];
        bf16x8 af[4], bfr[4];
#pragma unroll
        for (int i = 0; i < 4; ++i)
            af[i]  = *(const bf16x8*)&buf[((wm + i * 16 + lm) * 4 + sw) * 8];
#pragma unroll
        for (int i = 0; i < 4; ++i)
            bfr[i] = *(const bf16x8*)&buf[4096 + ((wn + i * 16 + lm) * 4 + sw) * 8];

#pragma unroll
        for (int i = 0; i < 4; ++i)
#pragma unroll
            for (int j = 0; j < 4; ++j)           // SWAPPED: D = C^T tile
                acc[i][j] = __builtin_amdgcn_mfma_f32_16x16x32_bf16(
                    bfr[i], af[j], acc[i][j], 0, 0, 0);

        cur = (cur == 2) ? 0 : cur + 1;
        pf  = (pf  == 2) ? 0 : pf  + 1;
    }

    const int mb = bm * 128 + wm + lm;
    const int nb = bn * 128 + wn + lq * 4;
#pragma unroll
    for (int i = 0; i < 4; ++i) {
        const int n = nb + i * 16;
        if (MODE == 0) {
#pragma unroll
            for (int j = 0; j < 4; ++j) {
                const int m = mb + j * 16;
                const uint32_t lo = (uint32_t)f2bf(acc[i][j][0] * scale) |
                                    ((uint32_t)f2bf(acc[i][j][1] * scale) << 16);
                const uint32_t hi = (uint32_t)f2bf(acc[i][j][2] * scale) |
                                    ((uint32_t)f2bf(acc[i][j][3] * scale) << 16);
                *(uint2*)&((uint16_t*)C0)[(long)bz * bsC + (long)m * ldc + n] =
                    make_uint2(lo, hi);
            }
        } else { // MODE 3: whole block lives in one section (bn-uniform)
            const int sec = n >> 9, nn = n & 511;
            const float* bp = sec == 0 ? bias0 : (sec == 1 ? bias1 : bias2);
            const float4 b4 = *(const float4*)&bp[nn];
#pragma unroll
            for (int j = 0; j < 4; ++j) {
                const int m = mb + j * 16;
                if (sec < 2) {
                    uint16_t* Cq = (uint16_t*)(sec == 0 ? C0 : C1);
                    const uint32_t lo = (uint32_t)f2bf(acc[i][j][0] + b4.x) |
                                        ((uint32_t)f2bf(acc[i][j][1] + b4.y) << 16);
                    const uint32_t hi = (uint32_t)f2bf(acc[i][j][2] + b4.z) |
                                        ((uint32_t)f2bf(acc[i][j][3] + b4.w) << 16);
                    *(uint2*)&Cq[(long)m * 512 + nn] = make_uint2(lo, hi);
                } else { // V transposed: Vt[b][d][s], d = nn+r, s = m
                    const int bb = m >> 11, ss = m & 2047;
                    uint16_t* vt = (uint16_t*)C2 + ((long)bb * 512 + nn) * 2048 + ss;
                    vt[0]        = f2bf(acc[i][j][0] + b4.x);
                    vt[2048]     = f2bf(acc[i][j][1] + b4.y);
                    vt[2 * 2048] = f2bf(acc[i][j][2] + b4.z);
                    vt[3 * 2048] = f2bf(acc[i][j][3] + b4.w);
                }
            }
        }
    }
}

// ---------------------------------------------------------------------------
// 256x256 / 8-wave NT GEMM, barrier-light (R10 schedule). MODE 4 epilogue:
// P = exp(acc*scale) bf16 + R11: f32 row-sums accumulated and atomicAdd'ed
// into rowsum[bz*2048 + m] (softmax denominator; buffer pre-zeroed by
// hipMemsetAsync). Each thread holds 16 exp values per output row m (4 i x
// 4 regs); butterfly over lane bits 4,5 (lq) sums the wave's 64-col slice;
// lanes lq==0 issue one atomicAdd per (row, wave). j-outer store order keeps
// each row's 128B span in 4 adjacent stores (no partial-line eviction).
// ---------------------------------------------------------------------------
template <int MODE>
__global__ __launch_bounds__(512, 2) void gemm_nt8(
    const uint16_t* __restrict__ A, const uint16_t* __restrict__ Bm,
    void* __restrict__ C0, float* __restrict__ rowsum,
    float scale, int K, int ldc, long bsA, long bsB, long bsC,
    int scols, int stPerBatch)
{
    __shared__ __align__(16) uint16_t SH[3][16384];

    const uint32_t id  = blockIdx.x;
    const uint32_t xcd = id & 7u;
    const uint32_t p   = id >> 3;
    const uint32_t q   = p >> 4;
    const uint32_t w   = p & 15u;
    const uint32_t g   = q * 8u + xcd;
    const uint32_t bz  = g / (uint32_t)stPerBatch;
    const uint32_t gs  = g - bz * (uint32_t)stPerBatch;
    const uint32_t sr  = gs / (uint32_t)scols;
    const uint32_t sc  = gs - sr * (uint32_t)scols;
    const int bm = (int)(sr * 4u + (w >> 2));
    const int bn = (int)(sc * 4u + (w & 3u));

    const int t  = threadIdx.x;
    const int wave = t >> 6, lane = t & 63;
    const int wm2 = (wave >> 2) * 128;            // row half   (0,128)
    const int wn2 = (wave & 3) * 64;              // col quarter(0..192)
    const int lm = lane & 15, lq = lane >> 4;
    const int sw = lq ^ ((lm >> 1) & 3);

    const uint16_t* Ab = A  + (long)bz * bsA + (long)bm * 256 * K;
    const uint16_t* Bb = Bm + (long)bz * bsB + (long)bn * 256 * K;

    long goff[2]; int loff[2];
#pragma unroll
    for (int j = 0; j < 2; ++j) {
        const int s  = j * 512 + t;
        const int r  = s >> 2;
        const int cs = s & 3;
        const int cg = cs ^ ((r >> 1) & 3);
        goff[j] = (long)r * K + cg * 8;
        loff[j] = s * 8;
    }

    const int KI = K >> 5;

#pragma unroll
    for (int st = 0; st < 2; ++st)
#pragma unroll
        for (int j = 0; j < 2; ++j) {
            cp16(Ab + goff[j] + st * 32, SH[st] + loff[j]);
            cp16(Bb + goff[j] + st * 32, SH[st] + 8192 + loff[j]);
        }

    f32x4 acc[4][8] = {};

    int cur = 0, pf = 2;
    for (int k = 0; k < KI; ++k) {
        asm volatile("s_waitcnt vmcnt(4) lgkmcnt(0)\n\ts_barrier" ::: "memory");

        int kp = k + 2; if (kp >= KI) kp = KI - 1;
        uint16_t* dst = SH[pf];
        const long ko = (long)kp * 32;
#pragma unroll
        for (int j = 0; j < 2; ++j) {
            cp16(Ab + goff[j] + ko, dst + loff[j]);
            cp16(Bb + goff[j] + ko, dst + 8192 + loff[j]);
        }

        const uint16_t* buf = SH[cur];
        bf16x8 af[8], bfr[4];
#define RDA(jj) (*(const bf16x8*)&buf[((wm2 + (jj) * 16 + lm) * 4 + sw) * 8])
#define RDB(ii) (*(const bf16x8*)&buf[8192 + ((wn2 + (ii) * 16 + lm) * 4 + sw) * 8])
        bfr[0] = RDB(0); bfr[1] = RDB(1); bfr[2] = RDB(2); bfr[3] = RDB(3);
        af[0] = RDA(0); af[1] = RDA(1); af[2] = RDA(2); af[3] = RDA(3);
        af[4] = RDA(4); af[5] = RDA(5); af[6] = RDA(6); af[7] = RDA(7);
#pragma unroll
        for (int pp = 0; pp < 4; ++pp) {
            __builtin_amdgcn_s_setprio(1);
#pragma unroll
            for (int i = 0; i < 4; ++i) {
                acc[i][2 * pp]     = __builtin_amdgcn_mfma_f32_16x16x32_bf16(
                    bfr[i], af[2 * pp],     acc[i][2 * pp],     0, 0, 0);
                acc[i][2 * pp + 1] = __builtin_amdgcn_mfma_f32_16x16x32_bf16(
                    bfr[i], af[2 * pp + 1], acc[i][2 * pp + 1], 0, 0, 0);
            }
            __builtin_amdgcn_s_setprio(0);
        }
#undef RDA
#undef RDB

        cur = (cur == 2) ? 0 : cur + 1;
        pf  = (pf  == 2) ? 0 : pf  + 1;
    }

    // epilogue: C^T layout; m = row (lane&15 based), n = col (lq*4 based)
    const int mb = bm * 256 + wm2 + lm;
    const int nb = bn * 256 + wn2 + lq * 4;
#pragma unroll
    for (int j = 0; j < 8; ++j) {
        const int m = mb + j * 16;
        float rsj = 0.f;
#pragma unroll
        for (int i = 0; i < 4; ++i) {
            const int n = nb + i * 16;
            const float v0 = __expf(acc[i][j][0] * scale);
            const float v1 = __expf(acc[i][j][1] * scale);
            const float v2 = __expf(acc[i][j][2] * scale);
            const float v3 = __expf(acc[i][j][3] * scale);
            rsj += (v0 + v1) + (v2 + v3);
            const uint32_t lo = (uint32_t)f2bf(v0) | ((uint32_t)f2bf(v1) << 16);
            const uint32_t hi = (uint32_t)f2bf(v2) | ((uint32_t)f2bf(v3) << 16);
            *(uint2*)&((uint16_t*)C0)[(long)bz * bsC + (long)m * ldc + n] =
                make_uint2(lo, hi);
        }
        // sum this wave's 64-col slice of row m across lq (lane bits 4,5)
        rsj += __shfl_xor(rsj, 16);
        rsj += __shfl_xor(rsj, 32);
        if (lq == 0)
            atomicAdd(&rowsum[(long)bz * 2048 + m], rsj);
    }
}

// ---------------------------------------------------------------------------
// R11: 64x128 / 4-wave NT GEMM for the skinny-N stages (PV, final proj).
// Wave-tile 32x64 (2M x 2N waves). BK=32, 3-stage circular (3 x 12 KB =
// 36 KB) -> 4 blocks/CU = 16 waves/CU (2x PV's previous occupancy; PV only
// has 1024 blocks at this tile). 3 cp16/thread/iter -> guard vmcnt(3)
// (stage k landed; k+1 in flight; k+2 issued after guard). Same verified
// XOR staging/read swizzle and circular WAR/RAW argument as gemm_nt.
// MODE 6: bf16 out * (1/rowsum[row])  (PV with precomputed denominator)
// MODE 2: f32 out + bias              (final projection)
// ---------------------------------------------------------------------------
template <int MODE>
__global__ __launch_bounds__(256, 4) void gemm_pv(
    const uint16_t* __restrict__ A, const uint16_t* __restrict__ Bm,
    void* __restrict__ C0, const float* __restrict__ aux, // rowsum | bias
    int K, int ldc, long bsA, long bsB, long bsC,
    int scols, int stPerBatch)
{
    // 3 stages x (A 64x32 = 4 KB | B 128x32 = 8 KB) = 36 KB
    __shared__ __align__(16) uint16_t SH[3][6144];

    const uint32_t id  = blockIdx.x;
    const uint32_t xcd = id & 7u;
    const uint32_t p   = id >> 3;
    const uint32_t q   = p >> 4;
    const uint32_t w   = p & 15u;
    const uint32_t g   = q * 8u + xcd;
    const uint32_t bz  = g / (uint32_t)stPerBatch;
    const uint32_t gs  = g - bz * (uint32_t)stPerBatch;
    const uint32_t sr  = gs / (uint32_t)scols;
    const uint32_t sc  = gs - sr * (uint32_t)scols;
    const int bm = (int)(sr * 4u + (w >> 2));     // M-tile 64
    const int bn = (int)(sc * 4u + (w & 3u));     // N-tile 128

    const int t  = threadIdx.x;
    const int wave = t >> 6, lane = t & 63;
    const int wm = (wave >> 1) * 32, wn = (wave & 1) * 64;
    const int lm = lane & 15, lq = lane >> 4;
    const int sw = lq ^ ((lm >> 1) & 3);

    const uint16_t* Ab = A  + (long)bz * bsA + (long)bm * 64 * K;
    const uint16_t* Bb = Bm + (long)bz * bsB + (long)bn * 128 * K;

    // staging: A 256 slots (s=t, rows 0..63), B 512 slots (s=j*256+t)
    const int rA  = t >> 2, csA = t & 3;
    const int cgA = csA ^ ((rA >> 1) & 3);
    const long goffA = (long)rA * K + cgA * 8;
    const int  loffA = t * 8;
    long goffB[2]; int loffB[2];
#pragma unroll
    for (int j = 0; j < 2; ++j) {
        const int s  = j * 256 + t;
        const int r  = s >> 2;
        const int cs = s & 3;
        const int cg = cs ^ ((r >> 1) & 3);
        goffB[j] = (long)r * K + cg * 8;
        loffB[j] = 2048 + s * 8;
    }

    const int KI = K >> 5;

    // prologue: stages 0,1 in flight (6 cp16/thread outstanding)
#pragma unroll
    for (int st = 0; st < 2; ++st) {
        cp16(Ab + goffA + st * 32, SH[st] + loffA);
        cp16(Bb + goffB[0] + st * 32, SH[st] + loffB[0]);
        cp16(Bb + goffB[1] + st * 32, SH[st] + loffB[1]);
    }

    f32x4 acc[4][2] = {};

    int cur = 0, pf = 2;
    for (int k = 0; k < KI; ++k) {
        // stage k landed (oldest 3 of 6 retired); my reads of buf (k+2)%3
        // (iter k-1) retired; barrier extends both block-wide.
        asm volatile("s_waitcnt vmcnt(3) lgkmcnt(0)\n\ts_barrier" ::: "memory");

        int kp = k + 2; if (kp >= KI) kp = KI - 1;
        uint16_t* dst = SH[pf];
        const long ko = (long)kp * 32;
        cp16(Ab + goffA + ko, dst + loffA);
        cp16(Bb + goffB[0] + ko, dst + loffB[0]);
        cp16(Bb + goffB[1] + ko, dst + loffB[1]);

        const uint16_t* buf = SH[cur];
        bf16x8 af[2], bfr[4];
#pragma unroll
        for (int j = 0; j < 2; ++j)               // A rows wm+j*16+lm
            af[j]  = *(const bf16x8*)&buf[((wm + j * 16 + lm) * 4 + sw) * 8];
#pragma unroll
        for (int i = 0; i < 4; ++i)               // B cols wn+i*16+lm
            bfr[i] = *(const bf16x8*)&buf[2048 + ((wn + i * 16 + lm) * 4 + sw) * 8];

#pragma unroll
        for (int i = 0; i < 4; ++i)
#pragma unroll
            for (int j = 0; j < 2; ++j)           // SWAPPED: D = C^T tile
                acc[i][j] = __builtin_amdgcn_mfma_f32_16x16x32_bf16(
                    bfr[i], af[j], acc[i][j], 0, 0, 0);

        cur = (cur == 2) ? 0 : cur + 1;
        pf  = (pf  == 2) ? 0 : pf  + 1;
    }

    // epilogue: C^T layout, j-outer (row-coalesced stores)
    const int mb = bm * 64 + wm + lm;
    const int nb = bn * 128 + wn + lq * 4;
#pragma unroll
    for (int j = 0; j < 2; ++j) {
        const int m = mb + j * 16;
        float inv;
        if (MODE == 6) inv = 1.f / aux[(long)bz * 2048 + m];
#pragma unroll
        for (int i = 0; i < 4; ++i) {
            const int n = nb + i * 16;
            if (MODE == 6) {
                const uint32_t lo = (uint32_t)f2bf(acc[i][j][0] * inv) |
                                    ((uint32_t)f2bf(acc[i][j][1] * inv) << 16);
                const uint32_t hi = (uint32_t)f2bf(acc[i][j][2] * inv) |
                                    ((uint32_t)f2bf(acc[i][j][3] * inv) << 16);
                *(uint2*)&((uint16_t*)C0)[(long)bz * bsC + (long)m * ldc + n] =
                    make_uint2(lo, hi);
            } else { // MODE 2: f32 + bias
                const float4 b4 = *(const float4*)&aux[n];
                *(float4*)&((float*)C0)[(long)m * ldc + n] = make_float4(
                    acc[i][j][0] + b4.x, acc[i][j][1] + b4.y,
                    acc[i][j][2] + b4.z, acc[i][j][3] + b4.w);
            }
        }
    }
}

// x + pos_table -> bf16, 8 elems/thread, exact grid (4096 blocks)
__global__ __launch_bounds__(256) void prep_x(const float* __restrict__ x,
                                              const float* __restrict__ pos,
                                              uint16_t* __restrict__ xb)
{
    const long i8 = ((long)blockIdx.x * 256 + threadIdx.x) * 8;
    const long p8 = i8 & ((1l << 20) - 1);   // S*D = 2^20
    const float4* xv = (const float4*)(x + i8);
    const float4* pv = (const float4*)(pos + p8);
    const float4 a0 = xv[0], a1 = xv[1];
    const float4 b0 = pv[0], b1 = pv[1];
    uint16_t o[8];
    o[0] = f2bf(a0.x + b0.x); o[1] = f2bf(a0.y + b0.y);
    o[2] = f2bf(a0.z + b0.z); o[3] = f2bf(a0.w + b0.w);
    o[4] = f2bf(a1.x + b1.x); o[5] = f2bf(a1.y + b1.y);
    o[6] = f2bf(a1.z + b1.z); o[7] = f2bf(a1.w + b1.w);
    *(uint4*)(xb + i8) = *(uint4*)o;
}

// Wq,Wk,Wv -> stacked wqkv[1536,512] bf16; Wd -> wd bf16. 512 blocks exact.
__global__ __launch_bounds__(256) void prep_w(
    const float* __restrict__ Wq, const float* __restrict__ Wk,
    const float* __restrict__ Wv, const float* __restrict__ Wd,
    uint16_t* __restrict__ wqkv, uint16_t* __restrict__ wd)
{
    const long f = ((long)blockIdx.x * 256 + threadIdx.x) * 8;
    const int  w = (int)(f >> 18);          // 262144 elems per weight
    const long off = f & 262143;
    const float* src = (w == 0) ? Wq : (w == 1) ? Wk : (w == 2) ? Wv : Wd;
    uint16_t* dst = (w < 3) ? (wqkv + (long)w * 262144 + off) : (wd + off);
    const float4* s4 = (const float4*)(src + off);
    const float4 a = s4[0], b = s4[1];
    uint16_t o[8];
    o[0] = f2bf(a.x); o[1] = f2bf(a.y); o[2] = f2bf(a.z); o[3] = f2bf(a.w);
    o[4] = f2bf(b.x); o[5] = f2bf(b.y); o[6] = f2bf(b.z); o[7] = f2bf(b.w);
    *(uint4*)dst = *(uint4*)o;
}

extern "C" void kernel_launch(void* const* d_in, const int* in_sizes, int n_in,
                              void* d_out, int out_size, void* d_ws, size_t ws_size,
                              hipStream_t stream)
{
    const float* x   = (const float*)d_in[0];
    const float* pos = (const float*)d_in[1];
    const float* Wq  = (const float*)d_in[2];
    const float* bq  = (const float*)d_in[3];
    const float* Wk  = (const float*)d_in[4];
    const float* bk  = (const float*)d_in[5];
    const float* Wv  = (const float*)d_in[6];
    const float* bv  = (const float*)d_in[7];
    const float* Wd  = (const float*)d_in[8];
    const float* bd  = (const float*)d_in[9];
    float* out = (float*)d_out;

    // workspace layout (bytes), total 153,092,096
    char* ws = (char*)d_ws;
    uint16_t* xb   = (uint16_t*)(ws);                 // 16,777,216  [16384,512]
    uint16_t* wqkv = (uint16_t*)(ws + 16777216);      //  1,572,864  [1536,512]
    uint16_t* wd   = (uint16_t*)(ws + 18350080);      //    524,288  [512,512]
    uint16_t* Qb   = (uint16_t*)(ws + 18874368);      // 16,777,216  [16384,512]
    uint16_t* Kb   = (uint16_t*)(ws + 35651584);      // 16,777,216  [16384,512]
    uint16_t* Vt   = (uint16_t*)(ws + 52428800);      // 16,777,216  [8,512,2048]
    uint16_t* Pb   = (uint16_t*)(ws + 69206016);      // 67,108,864  [8,2048,2048]
    uint16_t* yb   = (uint16_t*)(ws + 136314880);     // 16,777,216  [16384,512]
    // rowsum[16384] f32 (64 KB) reuses xb's region -- xb is dead after QKV.
    float* rowsum = (float*)ws;

    prep_x<<<4096, 256, 0, stream>>>(x, pos, xb);
    prep_w<<<512, 256, 0, stream>>>(Wq, Wk, Wv, Wd, wqkv, wd);

    // Q|K|Vt = xb @ wqkv^T (+bias):  M=16384, N=1536, K=512
    gemm_nt<3><<<1536, 256, 0, stream>>>(
        xb, wqkv, Qb, Kb, Vt, bq, bk, bv, 1.0f, 512, 512, 0, 0, 0, 3, 96);

    // zero softmax-denominator accumulator (xb region now dead)
    hipMemsetAsync(rowsum, 0, 16384 * sizeof(float), stream);

    // P[b] = exp((Q[b] @ K[b]^T) * scale), rowsum += per-row sums (atomics)
    // 8 x [2048,2048], K=512: per batch gm=8, gn=8 -> scols=2, stPerBatch=4
    gemm_nt8<4><<<512, 512, 0, stream>>>(
        Qb, Kb, Pb, rowsum, QK_SCALE, 512, 2048, (long)2048 * 512,
        (long)2048 * 512, (long)2048 * 2048, 2, 4);

    // y[b] = (P[b] @ Vt[b]^T) * (1/rowsum):  8 x [2048,512], K=2048
    // 64x128 tile: per batch gm=32, gn=4 -> scols=1, stPerBatch=8, 1024 blk
    gemm_pv<6><<<1024, 256, 0, stream>>>(
        Pb, Vt, yb, rowsum, 2048, 512, (long)2048 * 2048, (long)512 * 2048,
        (long)2048 * 512, 1, 8);

    // out = y @ wd^T + bd:  M=16384, N=512, K=512, fp32 out
    // 64x128 tile: gm=256, gn=4 -> scols=1, stPerBatch=64, 1024 blocks
    gemm_pv<2><<<1024, 256, 0, stream>>>(
        yb, wd, out, bd, 512, 512, 0, 0, 0, 1, 64);
}

// Round 6
// 261.924 us; speedup vs baseline: 1.1304x; 1.1304x over previous
//
#include <hip/hip_runtime.h>
#include <stdint.h>

typedef __bf16 bf16x8 __attribute__((ext_vector_type(8)));
typedef float f32x4 __attribute__((ext_vector_type(4)));

static constexpr float QK_SCALE = 0.044194173824159216f; // 1/sqrt(512)

__device__ __forceinline__ uint16_t f2bf(float f) {
    uint32_t x = __builtin_bit_cast(uint32_t, f);
    x += 0x7FFFu + ((x >> 16) & 1u);     // round-to-nearest-even; inputs finite
    return (uint16_t)(x >> 16);
}

// async 16B global->LDS copy (global_load_lds_dwordx4). LDS dest is
// wave-uniform base + lane*16; lds ptr = region_base + lane*16 matches.
__device__ __forceinline__ void cp16(const uint16_t* g, uint16_t* l) {
    __builtin_amdgcn_global_load_lds(
        (__attribute__((address_space(1))) void*)(uint16_t*)g,
        (__attribute__((address_space(3))) void*)l,
        16, 0, 0);
}

// ---------------------------------------------------------------------------
// NT GEMM: C[M,N] = A[M,K] * B[N,K]^T  (both K-contiguous, bf16)
// 128x128 block tile, BK=32, 256 thr = 4 waves (2x2), 64x64/wave.
// 3-stage circular LDS pipeline (48 KB) -> 3 blocks/CU. One guard per iter:
// vmcnt(4)+lgkmcnt(0)+s_barrier (stage k landed; k+1,k+2 stay in flight).
// XOR-swizzled 16B chunks (0 bank conflicts, verified). XCD supertile
// swizzle. MFMA operands swapped -> C^T layout -> packed stores.
// R12 post-mortem of R11: 64x128 PV tile regressed (halved MFMA/iter at
// constant guard cost; 1.5x staging traffic, FETCH 66->99 MB). PV returns
// to this 128^2 structure (R10-measured 54 us) with the lighter epilogue:
// MODE 2: f32 out + bias0 (final projection)
// MODE 3: QKV split epilogue: n<512 -> Q, <1024 -> K, else V transposed
// MODE 6: bf16 out * (1/rowsum[row]) (PV; denominator precomputed by QK^T)
// ---------------------------------------------------------------------------
template <int MODE>
__global__ __launch_bounds__(256, 3) void gemm_nt(
    const uint16_t* __restrict__ A, const uint16_t* __restrict__ Bm,
    void* __restrict__ C0, void* __restrict__ C1, void* __restrict__ C2,
    const float* __restrict__ bias0, const float* __restrict__ bias1,
    const float* __restrict__ bias2,
    float scale, int K, int ldc, long bsA, long bsB, long bsC,
    int scols, int stPerBatch)
{
    __shared__ __align__(16) uint16_t SH[3][8192];

    const uint32_t id  = blockIdx.x;
    const uint32_t xcd = id & 7u;
    const uint32_t p   = id >> 3;
    const uint32_t q   = p >> 4;
    const uint32_t w   = p & 15u;
    const uint32_t g   = q * 8u + xcd;
    const uint32_t bz  = g / (uint32_t)stPerBatch;
    const uint32_t gs  = g - bz * (uint32_t)stPerBatch;
    const uint32_t sr  = gs / (uint32_t)scols;
    const uint32_t sc  = gs - sr * (uint32_t)scols;
    const int bm = (int)(sr * 4u + (w >> 2));
    const int bn = (int)(sc * 4u + (w & 3u));

    const int t  = threadIdx.x;
    const int wave = t >> 6, lane = t & 63;
    const int wm = (wave >> 1) * 64, wn = (wave & 1) * 64;
    const int lm = lane & 15, lq = lane >> 4;
    const int sw = lq ^ ((lm >> 1) & 3);          // read-side swizzled k-group

    const uint16_t* Ab = A  + (long)bz * bsA + (long)bm * 128 * K;
    const uint16_t* Bb = Bm + (long)bz * bsB + (long)bn * 128 * K;

    long goff[2]; int loff[2];
#pragma unroll
    for (int j = 0; j < 2; ++j) {
        const int s  = j * 256 + t;
        const int r  = s >> 2;
        const int cs = s & 3;
        const int cg = cs ^ ((r >> 1) & 3);
        goff[j] = (long)r * K + cg * 8;
        loff[j] = s * 8;
    }

    const int KI = K >> 5;

#pragma unroll
    for (int st = 0; st < 2; ++st)
#pragma unroll
        for (int j = 0; j < 2; ++j) {
            cp16(Ab + goff[j] + st * 32, SH[st] + loff[j]);
            cp16(Bb + goff[j] + st * 32, SH[st] + 4096 + loff[j]);
        }

    f32x4 acc[4][4] = {};

    int cur = 0, pf = 2;
    for (int k = 0; k < KI; ++k) {
        asm volatile("s_waitcnt vmcnt(4) lgkmcnt(0)\n\ts_barrier" ::: "memory");

        int kp = k + 2; if (kp >= KI) kp = KI - 1;
        uint16_t* dst = SH[pf];
        const long ko = (long)kp * 32;
#pragma unroll
        for (int j = 0; j < 2; ++j) {
            cp16(Ab + goff[j] + ko, dst + loff[j]);
            cp16(Bb + goff[j] + ko, dst + 4096 + loff[j]);
        }

        const uint16_t* buf = SH[cur];
        bf16x8 af[4], bfr[4];
#pragma unroll
        for (int i = 0; i < 4; ++i)
            af[i]  = *(const bf16x8*)&buf[((wm + i * 16 + lm) * 4 + sw) * 8];
#pragma unroll
        for (int i = 0; i < 4; ++i)
            bfr[i] = *(const bf16x8*)&buf[4096 + ((wn + i * 16 + lm) * 4 + sw) * 8];

#pragma unroll
        for (int i = 0; i < 4; ++i)
#pragma unroll
            for (int j = 0; j < 4; ++j)           // SWAPPED: D = C^T tile
                acc[i][j] = __builtin_amdgcn_mfma_f32_16x16x32_bf16(
                    bfr[i], af[j], acc[i][j], 0, 0, 0);

        cur = (cur == 2) ? 0 : cur + 1;
        pf  = (pf  == 2) ? 0 : pf  + 1;
    }

    // epilogue: C^T layout -> lane holds n = nb+i*16+r (r=0..3 consecutive),
    // m = mb+j*16. Packed 8B/16B stores.
    const int mb = bm * 128 + wm + lm;
    const int nb = bn * 128 + wn + lq * 4;
    if (MODE == 6) {
        // j-outer: inv computed once per row, row's 64B span in 4 adj stores
#pragma unroll
        for (int j = 0; j < 4; ++j) {
            const int m = mb + j * 16;
            const float inv = 1.f / bias0[(long)bz * 2048 + m];
#pragma unroll
            for (int i = 0; i < 4; ++i) {
                const int n = nb + i * 16;
                const uint32_t lo = (uint32_t)f2bf(acc[i][j][0] * inv) |
                                    ((uint32_t)f2bf(acc[i][j][1] * inv) << 16);
                const uint32_t hi = (uint32_t)f2bf(acc[i][j][2] * inv) |
                                    ((uint32_t)f2bf(acc[i][j][3] * inv) << 16);
                *(uint2*)&((uint16_t*)C0)[(long)bz * bsC + (long)m * ldc + n] =
                    make_uint2(lo, hi);
            }
        }
        return;
    }
#pragma unroll
    for (int i = 0; i < 4; ++i) {
        const int n = nb + i * 16;
        if (MODE == 2) {
            const float4 b4 = *(const float4*)&bias0[n];
#pragma unroll
            for (int j = 0; j < 4; ++j) {
                const int m = mb + j * 16;
                *(float4*)&((float*)C0)[(long)m * ldc + n] = make_float4(
                    acc[i][j][0] + b4.x, acc[i][j][1] + b4.y,
                    acc[i][j][2] + b4.z, acc[i][j][3] + b4.w);
            }
        } else { // MODE 3: whole block lives in one section (bn-uniform)
            const int sec = n >> 9, nn = n & 511;
            const float* bp = sec == 0 ? bias0 : (sec == 1 ? bias1 : bias2);
            const float4 b4 = *(const float4*)&bp[nn];
#pragma unroll
            for (int j = 0; j < 4; ++j) {
                const int m = mb + j * 16;
                if (sec < 2) {
                    uint16_t* Cq = (uint16_t*)(sec == 0 ? C0 : C1);
                    const uint32_t lo = (uint32_t)f2bf(acc[i][j][0] + b4.x) |
                                        ((uint32_t)f2bf(acc[i][j][1] + b4.y) << 16);
                    const uint32_t hi = (uint32_t)f2bf(acc[i][j][2] + b4.z) |
                                        ((uint32_t)f2bf(acc[i][j][3] + b4.w) << 16);
                    *(uint2*)&Cq[(long)m * 512 + nn] = make_uint2(lo, hi);
                } else { // V transposed: Vt[b][d][s], d = nn+r, s = m
                    const int bb = m >> 11, ss = m & 2047;
                    uint16_t* vt = (uint16_t*)C2 + ((long)bb * 512 + nn) * 2048 + ss;
                    vt[0]        = f2bf(acc[i][j][0] + b4.x);
                    vt[2048]     = f2bf(acc[i][j][1] + b4.y);
                    vt[2 * 2048] = f2bf(acc[i][j][2] + b4.z);
                    vt[3 * 2048] = f2bf(acc[i][j][3] + b4.w);
                }
            }
        }
    }
}

// ---------------------------------------------------------------------------
// 256x256 / 8-wave NT GEMM, barrier-light (R10 schedule, verified). MODE 4
// epilogue: P = exp(acc*scale) bf16 + f32 row-sums atomicAdd'ed into
// rowsum[bz*2048+m] (softmax denominator; buffer pre-zeroed). Each thread
// holds 16 exp values per output row (4 i x 4 regs); butterfly over lane
// bits 4,5 sums the wave's 64-col slice; lq==0 lanes issue one atomicAdd
// per (row, wave). j-outer store order: row's 128B span in 4 adj stores.
// ---------------------------------------------------------------------------
template <int MODE>
__global__ __launch_bounds__(512, 2) void gemm_nt8(
    const uint16_t* __restrict__ A, const uint16_t* __restrict__ Bm,
    void* __restrict__ C0, float* __restrict__ rowsum,
    float scale, int K, int ldc, long bsA, long bsB, long bsC,
    int scols, int stPerBatch)
{
    __shared__ __align__(16) uint16_t SH[3][16384];

    const uint32_t id  = blockIdx.x;
    const uint32_t xcd = id & 7u;
    const uint32_t p   = id >> 3;
    const uint32_t q   = p >> 4;
    const uint32_t w   = p & 15u;
    const uint32_t g   = q * 8u + xcd;
    const uint32_t bz  = g / (uint32_t)stPerBatch;
    const uint32_t gs  = g - bz * (uint32_t)stPerBatch;
    const uint32_t sr  = gs / (uint32_t)scols;
    const uint32_t sc  = gs - sr * (uint32_t)scols;
    const int bm = (int)(sr * 4u + (w >> 2));
    const int bn = (int)(sc * 4u + (w & 3u));

    const int t  = threadIdx.x;
    const int wave = t >> 6, lane = t & 63;
    const int wm2 = (wave >> 2) * 128;            // row half   (0,128)
    const int wn2 = (wave & 3) * 64;              // col quarter(0..192)
    const int lm = lane & 15, lq = lane >> 4;
    const int sw = lq ^ ((lm >> 1) & 3);

    const uint16_t* Ab = A  + (long)bz * bsA + (long)bm * 256 * K;
    const uint16_t* Bb = Bm + (long)bz * bsB + (long)bn * 256 * K;

    long goff[2]; int loff[2];
#pragma unroll
    for (int j = 0; j < 2; ++j) {
        const int s  = j * 512 + t;
        const int r  = s >> 2;
        const int cs = s & 3;
        const int cg = cs ^ ((r >> 1) & 3);
        goff[j] = (long)r * K + cg * 8;
        loff[j] = s * 8;
    }

    const int KI = K >> 5;

#pragma unroll
    for (int st = 0; st < 2; ++st)
#pragma unroll
        for (int j = 0; j < 2; ++j) {
            cp16(Ab + goff[j] + st * 32, SH[st] + loff[j]);
            cp16(Bb + goff[j] + st * 32, SH[st] + 8192 + loff[j]);
        }

    f32x4 acc[4][8] = {};

    int cur = 0, pf = 2;
    for (int k = 0; k < KI; ++k) {
        asm volatile("s_waitcnt vmcnt(4) lgkmcnt(0)\n\ts_barrier" ::: "memory");

        int kp = k + 2; if (kp >= KI) kp = KI - 1;
        uint16_t* dst = SH[pf];
        const long ko = (long)kp * 32;
#pragma unroll
        for (int j = 0; j < 2; ++j) {
            cp16(Ab + goff[j] + ko, dst + loff[j]);
            cp16(Bb + goff[j] + ko, dst + 8192 + loff[j]);
        }

        const uint16_t* buf = SH[cur];
        bf16x8 af[8], bfr[4];
#define RDA(jj) (*(const bf16x8*)&buf[((wm2 + (jj) * 16 + lm) * 4 + sw) * 8])
#define RDB(ii) (*(const bf16x8*)&buf[8192 + ((wn2 + (ii) * 16 + lm) * 4 + sw) * 8])
        bfr[0] = RDB(0); bfr[1] = RDB(1); bfr[2] = RDB(2); bfr[3] = RDB(3);
        af[0] = RDA(0); af[1] = RDA(1); af[2] = RDA(2); af[3] = RDA(3);
        af[4] = RDA(4); af[5] = RDA(5); af[6] = RDA(6); af[7] = RDA(7);
#pragma unroll
        for (int pp = 0; pp < 4; ++pp) {
            __builtin_amdgcn_s_setprio(1);
#pragma unroll
            for (int i = 0; i < 4; ++i) {
                acc[i][2 * pp]     = __builtin_amdgcn_mfma_f32_16x16x32_bf16(
                    bfr[i], af[2 * pp],     acc[i][2 * pp],     0, 0, 0);
                acc[i][2 * pp + 1] = __builtin_amdgcn_mfma_f32_16x16x32_bf16(
                    bfr[i], af[2 * pp + 1], acc[i][2 * pp + 1], 0, 0, 0);
            }
            __builtin_amdgcn_s_setprio(0);
        }
#undef RDA
#undef RDB

        cur = (cur == 2) ? 0 : cur + 1;
        pf  = (pf  == 2) ? 0 : pf  + 1;
    }

    // epilogue: C^T layout; m = row (lane&15 based), n = col (lq*4 based)
    const int mb = bm * 256 + wm2 + lm;
    const int nb = bn * 256 + wn2 + lq * 4;
#pragma unroll
    for (int j = 0; j < 8; ++j) {
        const int m = mb + j * 16;
        float rsj = 0.f;
#pragma unroll
        for (int i = 0; i < 4; ++i) {
            const int n = nb + i * 16;
            const float v0 = __expf(acc[i][j][0] * scale);
            const float v1 = __expf(acc[i][j][1] * scale);
            const float v2 = __expf(acc[i][j][2] * scale);
            const float v3 = __expf(acc[i][j][3] * scale);
            rsj += (v0 + v1) + (v2 + v3);
            const uint32_t lo = (uint32_t)f2bf(v0) | ((uint32_t)f2bf(v1) << 16);
            const uint32_t hi = (uint32_t)f2bf(v2) | ((uint32_t)f2bf(v3) << 16);
            *(uint2*)&((uint16_t*)C0)[(long)bz * bsC + (long)m * ldc + n] =
                make_uint2(lo, hi);
        }
        // sum this wave's 64-col slice of row m across lq (lane bits 4,5)
        rsj += __shfl_xor(rsj, 16);
        rsj += __shfl_xor(rsj, 32);
        if (lq == 0)
            atomicAdd(&rowsum[(long)bz * 2048 + m], rsj);
    }
}

// x + pos_table -> bf16, 8 elems/thread, exact grid (4096 blocks)
__global__ __launch_bounds__(256) void prep_x(const float* __restrict__ x,
                                              const float* __restrict__ pos,
                                              uint16_t* __restrict__ xb)
{
    const long i8 = ((long)blockIdx.x * 256 + threadIdx.x) * 8;
    const long p8 = i8 & ((1l << 20) - 1);   // S*D = 2^20
    const float4* xv = (const float4*)(x + i8);
    const float4* pv = (const float4*)(pos + p8);
    const float4 a0 = xv[0], a1 = xv[1];
    const float4 b0 = pv[0], b1 = pv[1];
    uint16_t o[8];
    o[0] = f2bf(a0.x + b0.x); o[1] = f2bf(a0.y + b0.y);
    o[2] = f2bf(a0.z + b0.z); o[3] = f2bf(a0.w + b0.w);
    o[4] = f2bf(a1.x + b1.x); o[5] = f2bf(a1.y + b1.y);
    o[6] = f2bf(a1.z + b1.z); o[7] = f2bf(a1.w + b1.w);
    *(uint4*)(xb + i8) = *(uint4*)o;
}

// Wq,Wk,Wv -> stacked wqkv[1536,512] bf16; Wd -> wd bf16. 512 blocks exact.
__global__ __launch_bounds__(256) void prep_w(
    const float* __restrict__ Wq, const float* __restrict__ Wk,
    const float* __restrict__ Wv, const float* __restrict__ Wd,
    uint16_t* __restrict__ wqkv, uint16_t* __restrict__ wd)
{
    const long f = ((long)blockIdx.x * 256 + threadIdx.x) * 8;
    const int  w = (int)(f >> 18);          // 262144 elems per weight
    const long off = f & 262143;
    const float* src = (w == 0) ? Wq : (w == 1) ? Wk : (w == 2) ? Wv : Wd;
    uint16_t* dst = (w < 3) ? (wqkv + (long)w * 262144 + off) : (wd + off);
    const float4* s4 = (const float4*)(src + off);
    const float4 a = s4[0], b = s4[1];
    uint16_t o[8];
    o[0] = f2bf(a.x); o[1] = f2bf(a.y); o[2] = f2bf(a.z); o[3] = f2bf(a.w);
    o[4] = f2bf(b.x); o[5] = f2bf(b.y); o[6] = f2bf(b.z); o[7] = f2bf(b.w);
    *(uint4*)dst = *(uint4*)o;
}

extern "C" void kernel_launch(void* const* d_in, const int* in_sizes, int n_in,
                              void* d_out, int out_size, void* d_ws, size_t ws_size,
                              hipStream_t stream)
{
    const float* x   = (const float*)d_in[0];
    const float* pos = (const float*)d_in[1];
    const float* Wq  = (const float*)d_in[2];
    const float* bq  = (const float*)d_in[3];
    const float* Wk  = (const float*)d_in[4];
    const float* bk  = (const float*)d_in[5];
    const float* Wv  = (const float*)d_in[6];
    const float* bv  = (const float*)d_in[7];
    const float* Wd  = (const float*)d_in[8];
    const float* bd  = (const float*)d_in[9];
    float* out = (float*)d_out;

    // workspace layout (bytes), total 153,092,096
    char* ws = (char*)d_ws;
    uint16_t* xb   = (uint16_t*)(ws);                 // 16,777,216  [16384,512]
    uint16_t* wqkv = (uint16_t*)(ws + 16777216);      //  1,572,864  [1536,512]
    uint16_t* wd   = (uint16_t*)(ws + 18350080);      //    524,288  [512,512]
    uint16_t* Qb   = (uint16_t*)(ws + 18874368);      // 16,777,216  [16384,512]
    uint16_t* Kb   = (uint16_t*)(ws + 35651584);      // 16,777,216  [16384,512]
    uint16_t* Vt   = (uint16_t*)(ws + 52428800);      // 16,777,216  [8,512,2048]
    uint16_t* Pb   = (uint16_t*)(ws + 69206016);      // 67,108,864  [8,2048,2048]
    uint16_t* yb   = (uint16_t*)(ws + 136314880);     // 16,777,216  [16384,512]
    // rowsum[16384] f32 (64 KB) reuses xb's region -- xb is dead after QKV.
    float* rowsum = (float*)ws;

    prep_x<<<4096, 256, 0, stream>>>(x, pos, xb);
    prep_w<<<512, 256, 0, stream>>>(Wq, Wk, Wv, Wd, wqkv, wd);

    // Q|K|Vt = xb @ wqkv^T (+bias):  M=16384, N=1536, K=512
    gemm_nt<3><<<1536, 256, 0, stream>>>(
        xb, wqkv, Qb, Kb, Vt, bq, bk, bv, 1.0f, 512, 512, 0, 0, 0, 3, 96);

    // zero softmax-denominator accumulator (xb region now dead)
    hipMemsetAsync(rowsum, 0, 16384 * sizeof(float), stream);

    // P[b] = exp((Q[b] @ K[b]^T) * scale), rowsum += per-row sums (atomics)
    // 8 x [2048,2048], K=512: per batch gm=8, gn=8 -> scols=2, stPerBatch=4
    gemm_nt8<4><<<512, 512, 0, stream>>>(
        Qb, Kb, Pb, rowsum, QK_SCALE, 512, 2048, (long)2048 * 512,
        (long)2048 * 512, (long)2048 * 2048, 2, 4);

    // y[b] = (P[b] @ Vt[b]^T) * (1/rowsum):  8 x [2048,512], K=2048
    // 128^2 tile (R10-verified): per batch gm=16, gn=4 -> scols=1,
    // stPerBatch=4, blocks=512
    gemm_nt<6><<<512, 256, 0, stream>>>(
        Pb, Vt, yb, nullptr, nullptr, rowsum, nullptr, nullptr,
        1.0f, 2048, 512, (long)2048 * 2048, (long)512 * 2048,
        (long)2048 * 512, 1, 4);

    // out = y @ wd^T + bd:  M=16384, N=512, K=512, fp32 out
    // gm=128, gn=4 -> scols=1, stPerBatch=32, blocks=512
    gemm_nt<2><<<512, 256, 0, stream>>>(
        yb, wd, out, nullptr, nullptr, bd, nullptr, nullptr,
        1.0f, 512, 512, 0, 0, 0, 1, 32);
}

// Round 7
// 256.346 us; speedup vs baseline: 1.1550x; 1.0218x over previous
//
#include <hip/hip_runtime.h>
#include <stdint.h>

typedef __bf16 bf16x8 __attribute__((ext_vector_type(8)));
typedef float f32x4 __attribute__((ext_vector_type(4)));

static constexpr float QK_SCALE = 0.044194173824159216f; // 1/sqrt(512)

__device__ __forceinline__ uint16_t f2bf(float f) {
    uint32_t x = __builtin_bit_cast(uint32_t, f);
    x += 0x7FFFu + ((x >> 16) & 1u);     // round-to-nearest-even; inputs finite
    return (uint16_t)(x >> 16);
}

// async 16B global->LDS copy (global_load_lds_dwordx4). LDS dest is
// wave-uniform base + lane*16; lds ptr = region_base + lane*16 matches.
__device__ __forceinline__ void cp16(const uint16_t* g, uint16_t* l) {
    __builtin_amdgcn_global_load_lds(
        (__attribute__((address_space(1))) void*)(uint16_t*)g,
        (__attribute__((address_space(3))) void*)l,
        16, 0, 0);
}

// ---------------------------------------------------------------------------
// NT GEMM: C[M,N] = A[M,K] * B[N,K]^T  (both K-contiguous, bf16)
// 128x128 block tile, BK=32, 256 thr = 4 waves (2x2), 64x64/wave.
// 3-stage circular LDS pipeline (48 KB) -> 3 blocks/CU. One guard per iter:
// vmcnt(4)+lgkmcnt(0)+s_barrier (stage k landed; k+1,k+2 stay in flight).
// XOR-swizzled 16B chunks (0 bank conflicts, verified). XCD supertile
// swizzle. MFMA operands swapped -> C^T layout -> packed stores.
// MODE 2: f32 out + bias0 (final projection)
// MODE 3: QKV split epilogue: n<512 -> Q, <1024 -> K, else V transposed
// MODE 6: bf16 out * (1/rowsum[row]) (PV; denominator precomputed by QK^T)
// ---------------------------------------------------------------------------
template <int MODE>
__global__ __launch_bounds__(256, 3) void gemm_nt(
    const uint16_t* __restrict__ A, const uint16_t* __restrict__ Bm,
    void* __restrict__ C0, void* __restrict__ C1, void* __restrict__ C2,
    const float* __restrict__ bias0, const float* __restrict__ bias1,
    const float* __restrict__ bias2,
    float scale, int K, int ldc, long bsA, long bsB, long bsC,
    int scols, int stPerBatch)
{
    __shared__ __align__(16) uint16_t SH[3][8192];

    const uint32_t id  = blockIdx.x;
    const uint32_t xcd = id & 7u;
    const uint32_t p   = id >> 3;
    const uint32_t q   = p >> 4;
    const uint32_t w   = p & 15u;
    const uint32_t g   = q * 8u + xcd;
    const uint32_t bz  = g / (uint32_t)stPerBatch;
    const uint32_t gs  = g - bz * (uint32_t)stPerBatch;
    const uint32_t sr  = gs / (uint32_t)scols;
    const uint32_t sc  = gs - sr * (uint32_t)scols;
    const int bm = (int)(sr * 4u + (w >> 2));
    const int bn = (int)(sc * 4u + (w & 3u));

    const int t  = threadIdx.x;
    const int wave = t >> 6, lane = t & 63;
    const int wm = (wave >> 1) * 64, wn = (wave & 1) * 64;
    const int lm = lane & 15, lq = lane >> 4;
    const int sw = lq ^ ((lm >> 1) & 3);          // read-side swizzled k-group

    const uint16_t* Ab = A  + (long)bz * bsA + (long)bm * 128 * K;
    const uint16_t* Bb = Bm + (long)bz * bsB + (long)bn * 128 * K;

    long goff[2]; int loff[2];
#pragma unroll
    for (int j = 0; j < 2; ++j) {
        const int s  = j * 256 + t;
        const int r  = s >> 2;
        const int cs = s & 3;
        const int cg = cs ^ ((r >> 1) & 3);
        goff[j] = (long)r * K + cg * 8;
        loff[j] = s * 8;
    }

    const int KI = K >> 5;

#pragma unroll
    for (int st = 0; st < 2; ++st)
#pragma unroll
        for (int j = 0; j < 2; ++j) {
            cp16(Ab + goff[j] + st * 32, SH[st] + loff[j]);
            cp16(Bb + goff[j] + st * 32, SH[st] + 4096 + loff[j]);
        }

    f32x4 acc[4][4] = {};

    int cur = 0, pf = 2;
    for (int k = 0; k < KI; ++k) {
        asm volatile("s_waitcnt vmcnt(4) lgkmcnt(0)\n\ts_barrier" ::: "memory");

        int kp = k + 2; if (kp >= KI) kp = KI - 1;
        uint16_t* dst = SH[pf];
        const long ko = (long)kp * 32;
#pragma unroll
        for (int j = 0; j < 2; ++j) {
            cp16(Ab + goff[j] + ko, dst + loff[j]);
            cp16(Bb + goff[j] + ko, dst + 4096 + loff[j]);
        }

        const uint16_t* buf = SH[cur];
        bf16x8 af[4], bfr[4];
#pragma unroll
        for (int i = 0; i < 4; ++i)
            af[i]  = *(const bf16x8*)&buf[((wm + i * 16 + lm) * 4 + sw) * 8];
#pragma unroll
        for (int i = 0; i < 4; ++i)
            bfr[i] = *(const bf16x8*)&buf[4096 + ((wn + i * 16 + lm) * 4 + sw) * 8];

#pragma unroll
        for (int i = 0; i < 4; ++i)
#pragma unroll
            for (int j = 0; j < 4; ++j)           // SWAPPED: D = C^T tile
                acc[i][j] = __builtin_amdgcn_mfma_f32_16x16x32_bf16(
                    bfr[i], af[j], acc[i][j], 0, 0, 0);

        cur = (cur == 2) ? 0 : cur + 1;
        pf  = (pf  == 2) ? 0 : pf  + 1;
    }

    // epilogue: C^T layout -> lane holds n = nb+i*16+r (r=0..3 consecutive),
    // m = mb+j*16. Packed 8B/16B stores.
    const int mb = bm * 128 + wm + lm;
    const int nb = bn * 128 + wn + lq * 4;
    if (MODE == 6) {
        // j-outer: inv computed once per row, row's 64B span in 4 adj stores
#pragma unroll
        for (int j = 0; j < 4; ++j) {
            const int m = mb + j * 16;
            const float inv = 1.f / bias0[(long)bz * 2048 + m];
#pragma unroll
            for (int i = 0; i < 4; ++i) {
                const int n = nb + i * 16;
                const uint32_t lo = (uint32_t)f2bf(acc[i][j][0] * inv) |
                                    ((uint32_t)f2bf(acc[i][j][1] * inv) << 16);
                const uint32_t hi = (uint32_t)f2bf(acc[i][j][2] * inv) |
                                    ((uint32_t)f2bf(acc[i][j][3] * inv) << 16);
                *(uint2*)&((uint16_t*)C0)[(long)bz * bsC + (long)m * ldc + n] =
                    make_uint2(lo, hi);
            }
        }
        return;
    }
#pragma unroll
    for (int i = 0; i < 4; ++i) {
        const int n = nb + i * 16;
        if (MODE == 2) {
            const float4 b4 = *(const float4*)&bias0[n];
#pragma unroll
            for (int j = 0; j < 4; ++j) {
                const int m = mb + j * 16;
                *(float4*)&((float*)C0)[(long)m * ldc + n] = make_float4(
                    acc[i][j][0] + b4.x, acc[i][j][1] + b4.y,
                    acc[i][j][2] + b4.z, acc[i][j][3] + b4.w);
            }
        } else { // MODE 3: whole block lives in one section (bn-uniform)
            const int sec = n >> 9, nn = n & 511;
            const float* bp = sec == 0 ? bias0 : (sec == 1 ? bias1 : bias2);
            const float4 b4 = *(const float4*)&bp[nn];
#pragma unroll
            for (int j = 0; j < 4; ++j) {
                const int m = mb + j * 16;
                if (sec < 2) {
                    uint16_t* Cq = (uint16_t*)(sec == 0 ? C0 : C1);
                    const uint32_t lo = (uint32_t)f2bf(acc[i][j][0] + b4.x) |
                                        ((uint32_t)f2bf(acc[i][j][1] + b4.y) << 16);
                    const uint32_t hi = (uint32_t)f2bf(acc[i][j][2] + b4.z) |
                                        ((uint32_t)f2bf(acc[i][j][3] + b4.w) << 16);
                    *(uint2*)&Cq[(long)m * 512 + nn] = make_uint2(lo, hi);
                } else { // V transposed: Vt[b][d][s], d = nn+r, s = m
                    const int bb = m >> 11, ss = m & 2047;
                    uint16_t* vt = (uint16_t*)C2 + ((long)bb * 512 + nn) * 2048 + ss;
                    vt[0]        = f2bf(acc[i][j][0] + b4.x);
                    vt[2048]     = f2bf(acc[i][j][1] + b4.y);
                    vt[2 * 2048] = f2bf(acc[i][j][2] + b4.z);
                    vt[3 * 2048] = f2bf(acc[i][j][3] + b4.w);
                }
            }
        }
    }
}

// ---------------------------------------------------------------------------
// R13: QK^T kernel = 256x128 tile / 4 waves / 2 blocks per CU.
// R12 post-mortem: the 256^2 8-wave kernel is pinned at ~648 TF == the
// documented 2-phase-structure plateau; its 96 KB LDS forces 1 block/CU so
// guard stalls idle the whole CU. Every kernel here that beats it has
// independent co-resident blocks covering each other's stalls (128^2 @ 3/CU).
// This kernel keeps gemm_nt8's per-wave shape (128x64 out/wave: 12 ds_read +
// 32 MFMA per K-step -- same density) but tile 256x128 with 4 waves (2Mx2N):
// 3 stages x (A 256x32 = 16 KB | B 128x32 = 8 KB) = 72 KB -> 2 blocks/CU.
// 6 cp16/thread/iter -> guard vmcnt(6)+lgkmcnt(0)+barrier (stage k landed;
// stage k+1's 6 in flight; k+2 issued after guard). Same verified XOR
// staging map and circular 3-stage WAR/RAW argument. Grid: per batch
// 8x16 tiles -> 1024 blocks = exactly 2 resident rounds (scols=4, spb=8).
// Epilogue: P = exp(acc*scale) bf16 (j-outer: row's 128B in adjacent
// stores) + f32 row-sum butterfly over lq + one atomicAdd per (row,wave)
// into rowsum[bz*2048+m] (softmax denominator; pre-zeroed).
// ---------------------------------------------------------------------------
__global__ __launch_bounds__(256, 2) void gemm_qk(
    const uint16_t* __restrict__ A, const uint16_t* __restrict__ Bm,
    uint16_t* __restrict__ C0, float* __restrict__ rowsum,
    float scale, int K, int ldc, long bsA, long bsB, long bsC,
    int scols, int stPerBatch)
{
    // 3 stages x 24 KB (A 16 KB @ 0, B 8 KB @ 8192 uint16)
    __shared__ __align__(16) uint16_t SH[3][12288];

    const uint32_t id  = blockIdx.x;
    const uint32_t xcd = id & 7u;
    const uint32_t p   = id >> 3;
    const uint32_t q   = p >> 4;
    const uint32_t w   = p & 15u;
    const uint32_t g   = q * 8u + xcd;
    const uint32_t bz  = g / (uint32_t)stPerBatch;
    const uint32_t gs  = g - bz * (uint32_t)stPerBatch;
    const uint32_t sr  = gs / (uint32_t)scols;
    const uint32_t sc  = gs - sr * (uint32_t)scols;
    const int bm = (int)(sr * 4u + (w >> 2));     // M-tile 256
    const int bn = (int)(sc * 4u + (w & 3u));     // N-tile 128

    const int t  = threadIdx.x;
    const int wave = t >> 6, lane = t & 63;
    const int wm2 = (wave >> 1) * 128;            // row half (0,128)
    const int wn2 = (wave & 1) * 64;              // col half (0,64)
    const int lm = lane & 15, lq = lane >> 4;
    const int sw = lq ^ ((lm >> 1) & 3);          // read-side swizzled k-group

    const uint16_t* Ab = A  + (long)bz * bsA + (long)bm * 256 * K;
    const uint16_t* Bb = Bm + (long)bz * bsB + (long)bn * 128 * K;

    // staging map (verified XOR scheme): A = 1024 slots (4/thread),
    // B = 512 slots (2/thread, j=0,1 formulas identical to A's first two).
    long goff[4]; int loff[4];
#pragma unroll
    for (int j = 0; j < 4; ++j) {
        const int s  = j * 256 + t;
        const int r  = s >> 2;
        const int cs = s & 3;
        const int cg = cs ^ ((r >> 1) & 3);
        goff[j] = (long)r * K + cg * 8;
        loff[j] = s * 8;
    }

    const int KI = K >> 5;                        // 16

    // prologue: stages 0,1 in flight (12 cp16/thread outstanding)
#pragma unroll
    for (int st = 0; st < 2; ++st) {
#pragma unroll
        for (int j = 0; j < 4; ++j)
            cp16(Ab + goff[j] + st * 32, SH[st] + loff[j]);
#pragma unroll
        for (int j = 0; j < 2; ++j)
            cp16(Bb + goff[j] + st * 32, SH[st] + 8192 + loff[j]);
    }

    f32x4 acc[4][8] = {};

    int cur = 0, pf = 2;
    for (int k = 0; k < KI; ++k) {
        // stage k landed (oldest 6 of 12 outstanding retired); all my reads
        // of buf (k+2)%3 (iter k-1) retired; barrier extends block-wide.
        asm volatile("s_waitcnt vmcnt(6) lgkmcnt(0)\n\ts_barrier" ::: "memory");

        int kp = k + 2; if (kp >= KI) kp = KI - 1; // tail: refetch hot tile
        uint16_t* dst = SH[pf];
        const long ko = (long)kp * 32;
#pragma unroll
        for (int j = 0; j < 4; ++j)
            cp16(Ab + goff[j] + ko, dst + loff[j]);
#pragma unroll
        for (int j = 0; j < 2; ++j)
            cp16(Bb + goff[j] + ko, dst + 8192 + loff[j]);

        const uint16_t* buf = SH[cur];
        bf16x8 af[8], bfr[4];
#define RDA(jj) (*(const bf16x8*)&buf[((wm2 + (jj) * 16 + lm) * 4 + sw) * 8])
#define RDB(ii) (*(const bf16x8*)&buf[8192 + ((wn2 + (ii) * 16 + lm) * 4 + sw) * 8])
        bfr[0] = RDB(0); bfr[1] = RDB(1); bfr[2] = RDB(2); bfr[3] = RDB(3);
        af[0] = RDA(0); af[1] = RDA(1); af[2] = RDA(2); af[3] = RDA(3);
        af[4] = RDA(4); af[5] = RDA(5); af[6] = RDA(6); af[7] = RDA(7);
#pragma unroll
        for (int pp = 0; pp < 4; ++pp) {
            __builtin_amdgcn_s_setprio(1);
#pragma unroll
            for (int i = 0; i < 4; ++i) {
                acc[i][2 * pp]     = __builtin_amdgcn_mfma_f32_16x16x32_bf16(
                    bfr[i], af[2 * pp],     acc[i][2 * pp],     0, 0, 0);
                acc[i][2 * pp + 1] = __builtin_amdgcn_mfma_f32_16x16x32_bf16(
                    bfr[i], af[2 * pp + 1], acc[i][2 * pp + 1], 0, 0, 0);
            }
            __builtin_amdgcn_s_setprio(0);
        }
#undef RDA
#undef RDB

        cur = (cur == 2) ? 0 : cur + 1;
        pf  = (pf  == 2) ? 0 : pf  + 1;
    }

    // epilogue: C^T layout; m = row (lane&15 based), n = col (lq*4 based)
    const int mb = bm * 256 + wm2 + lm;
    const int nb = bn * 128 + wn2 + lq * 4;
#pragma unroll
    for (int j = 0; j < 8; ++j) {
        const int m = mb + j * 16;
        float rsj = 0.f;
#pragma unroll
        for (int i = 0; i < 4; ++i) {
            const int n = nb + i * 16;
            const float v0 = __expf(acc[i][j][0] * scale);
            const float v1 = __expf(acc[i][j][1] * scale);
            const float v2 = __expf(acc[i][j][2] * scale);
            const float v3 = __expf(acc[i][j][3] * scale);
            rsj += (v0 + v1) + (v2 + v3);
            const uint32_t lo = (uint32_t)f2bf(v0) | ((uint32_t)f2bf(v1) << 16);
            const uint32_t hi = (uint32_t)f2bf(v2) | ((uint32_t)f2bf(v3) << 16);
            *(uint2*)&C0[(long)bz * bsC + (long)m * ldc + n] =
                make_uint2(lo, hi);
        }
        // sum this wave's 64-col slice of row m across lq (lane bits 4,5)
        rsj += __shfl_xor(rsj, 16);
        rsj += __shfl_xor(rsj, 32);
        if (lq == 0)
            atomicAdd(&rowsum[(long)bz * 2048 + m], rsj);
    }
}

// x + pos_table -> bf16, 8 elems/thread, exact grid (4096 blocks)
__global__ __launch_bounds__(256) void prep_x(const float* __restrict__ x,
                                              const float* __restrict__ pos,
                                              uint16_t* __restrict__ xb)
{
    const long i8 = ((long)blockIdx.x * 256 + threadIdx.x) * 8;
    const long p8 = i8 & ((1l << 20) - 1);   // S*D = 2^20
    const float4* xv = (const float4*)(x + i8);
    const float4* pv = (const float4*)(pos + p8);
    const float4 a0 = xv[0], a1 = xv[1];
    const float4 b0 = pv[0], b1 = pv[1];
    uint16_t o[8];
    o[0] = f2bf(a0.x + b0.x); o[1] = f2bf(a0.y + b0.y);
    o[2] = f2bf(a0.z + b0.z); o[3] = f2bf(a0.w + b0.w);
    o[4] = f2bf(a1.x + b1.x); o[5] = f2bf(a1.y + b1.y);
    o[6] = f2bf(a1.z + b1.z); o[7] = f2bf(a1.w + b1.w);
    *(uint4*)(xb + i8) = *(uint4*)o;
}

// Wq,Wk,Wv -> stacked wqkv[1536,512] bf16; Wd -> wd bf16. 512 blocks exact.
__global__ __launch_bounds__(256) void prep_w(
    const float* __restrict__ Wq, const float* __restrict__ Wk,
    const float* __restrict__ Wv, const float* __restrict__ Wd,
    uint16_t* __restrict__ wqkv, uint16_t* __restrict__ wd)
{
    const long f = ((long)blockIdx.x * 256 + threadIdx.x) * 8;
    const int  w = (int)(f >> 18);          // 262144 elems per weight
    const long off = f & 262143;
    const float* src = (w == 0) ? Wq : (w == 1) ? Wk : (w == 2) ? Wv : Wd;
    uint16_t* dst = (w < 3) ? (wqkv + (long)w * 262144 + off) : (wd + off);
    const float4* s4 = (const float4*)(src + off);
    const float4 a = s4[0], b = s4[1];
    uint16_t o[8];
    o[0] = f2bf(a.x); o[1] = f2bf(a.y); o[2] = f2bf(a.z); o[3] = f2bf(a.w);
    o[4] = f2bf(b.x); o[5] = f2bf(b.y); o[6] = f2bf(b.z); o[7] = f2bf(b.w);
    *(uint4*)dst = *(uint4*)o;
}

extern "C" void kernel_launch(void* const* d_in, const int* in_sizes, int n_in,
                              void* d_out, int out_size, void* d_ws, size_t ws_size,
                              hipStream_t stream)
{
    const float* x   = (const float*)d_in[0];
    const float* pos = (const float*)d_in[1];
    const float* Wq  = (const float*)d_in[2];
    const float* bq  = (const float*)d_in[3];
    const float* Wk  = (const float*)d_in[4];
    const float* bk  = (const float*)d_in[5];
    const float* Wv  = (const float*)d_in[6];
    const float* bv  = (const float*)d_in[7];
    const float* Wd  = (const float*)d_in[8];
    const float* bd  = (const float*)d_in[9];
    float* out = (float*)d_out;

    // workspace layout (bytes), total 153,092,096
    char* ws = (char*)d_ws;
    uint16_t* xb   = (uint16_t*)(ws);                 // 16,777,216  [16384,512]
    uint16_t* wqkv = (uint16_t*)(ws + 16777216);      //  1,572,864  [1536,512]
    uint16_t* wd   = (uint16_t*)(ws + 18350080);      //    524,288  [512,512]
    uint16_t* Qb   = (uint16_t*)(ws + 18874368);      // 16,777,216  [16384,512]
    uint16_t* Kb   = (uint16_t*)(ws + 35651584);      // 16,777,216  [16384,512]
    uint16_t* Vt   = (uint16_t*)(ws + 52428800);      // 16,777,216  [8,512,2048]
    uint16_t* Pb   = (uint16_t*)(ws + 69206016);      // 67,108,864  [8,2048,2048]
    uint16_t* yb   = (uint16_t*)(ws + 136314880);     // 16,777,216  [16384,512]
    // rowsum[16384] f32 (64 KB) reuses xb's region -- xb is dead after QKV.
    float* rowsum = (float*)ws;

    prep_x<<<4096, 256, 0, stream>>>(x, pos, xb);
    prep_w<<<512, 256, 0, stream>>>(Wq, Wk, Wv, Wd, wqkv, wd);

    // Q|K|Vt = xb @ wqkv^T (+bias):  M=16384, N=1536, K=512
    gemm_nt<3><<<1536, 256, 0, stream>>>(
        xb, wqkv, Qb, Kb, Vt, bq, bk, bv, 1.0f, 512, 512, 0, 0, 0, 3, 96);

    // zero softmax-denominator accumulator (xb region now dead)
    hipMemsetAsync(rowsum, 0, 16384 * sizeof(float), stream);

    // P[b] = exp((Q[b] @ K[b]^T) * scale), rowsum += per-row sums (atomics)
    // 8 x [2048,2048], K=512 -- 256x128-tile 2-blocks/CU kernel:
    // per batch gm=8, gn=16 -> scols=4, stPerBatch=8, blocks=1024
    gemm_qk<<<1024, 256, 0, stream>>>(
        Qb, Kb, Pb, rowsum, QK_SCALE, 512, 2048, (long)2048 * 512,
        (long)2048 * 512, (long)2048 * 2048, 4, 8);

    // y[b] = (P[b] @ Vt[b]^T) * (1/rowsum):  8 x [2048,512], K=2048
    // 128^2 tile (verified): per batch gm=16, gn=4 -> scols=1,
    // stPerBatch=4, blocks=512
    gemm_nt<6><<<512, 256, 0, stream>>>(
        Pb, Vt, yb, nullptr, nullptr, rowsum, nullptr, nullptr,
        1.0f, 2048, 512, (long)2048 * 2048, (long)512 * 2048,
        (long)2048 * 512, 1, 4);

    // out = y @ wd^T + bd:  M=16384, N=512, K=512, fp32 out
    // gm=128, gn=4 -> scols=1, stPerBatch=32, blocks=512
    gemm_nt<2><<<512, 256, 0, stream>>>(
        yb, wd, out, nullptr, nullptr, bd, nullptr, nullptr,
        1.0f, 512, 512, 0, 0, 0, 1, 32);
}

// Round 8
// 254.300 us; speedup vs baseline: 1.1643x; 1.0080x over previous
//
#include <hip/hip_runtime.h>
#include <stdint.h>

typedef __bf16 bf16x8 __attribute__((ext_vector_type(8)));
typedef float f32x4 __attribute__((ext_vector_type(4)));

static constexpr float QK_SCALE = 0.044194173824159216f; // 1/sqrt(512)

__device__ __forceinline__ uint16_t f2bf(float f) {
    uint32_t x = __builtin_bit_cast(uint32_t, f);
    x += 0x7FFFu + ((x >> 16) & 1u);     // round-to-nearest-even; inputs finite
    return (uint16_t)(x >> 16);
}

// async 16B global->LDS copy (global_load_lds_dwordx4). LDS dest is
// wave-uniform base + lane*16; lds ptr = region_base + lane*16 matches.
__device__ __forceinline__ void cp16(const uint16_t* g, uint16_t* l) {
    __builtin_amdgcn_global_load_lds(
        (__attribute__((address_space(1))) void*)(uint16_t*)g,
        (__attribute__((address_space(3))) void*)l,
        16, 0, 0);
}

// ---------------------------------------------------------------------------
// NT GEMM: C[M,N] = A[M,K] * B[N,K]^T  (both K-contiguous, bf16)
// 128x128 block tile, BK=32, 256 thr = 4 waves (2x2), 64x64/wave.
// 3-stage circular LDS pipeline (48 KB) -> 3 blocks/CU. One guard per iter:
// vmcnt(4)+lgkmcnt(0)+s_barrier (stage k landed; k+1,k+2 stay in flight).
// XOR-swizzled 16B chunks (0 bank conflicts, verified). XCD supertile
// swizzle. MFMA operands swapped -> C^T layout -> packed stores.
// R14: softmax normalization moved to proj epilogue (row scalar factors out
// of the d-contraction): PV = bare MODE 0; proj = MODE 7 (f32, *inv + bias).
// MODE 0: bf16 out, batched, scale (PV: scale=1)
// MODE 3: QKV split epilogue: n<512 -> Q, <1024 -> K, else V transposed
// MODE 7: f32 out * (1/rowsum[m]) + bias0 (final projection + softmax denom)
// ---------------------------------------------------------------------------
template <int MODE>
__global__ __launch_bounds__(256, 3) void gemm_nt(
    const uint16_t* __restrict__ A, const uint16_t* __restrict__ Bm,
    void* __restrict__ C0, void* __restrict__ C1, void* __restrict__ C2,
    const float* __restrict__ bias0, const float* __restrict__ bias1,
    const float* __restrict__ bias2,
    float scale, int K, int ldc, long bsA, long bsB, long bsC,
    int scols, int stPerBatch)
{
    __shared__ __align__(16) uint16_t SH[3][8192];

    const uint32_t id  = blockIdx.x;
    const uint32_t xcd = id & 7u;
    const uint32_t p   = id >> 3;
    const uint32_t q   = p >> 4;
    const uint32_t w   = p & 15u;
    const uint32_t g   = q * 8u + xcd;
    const uint32_t bz  = g / (uint32_t)stPerBatch;
    const uint32_t gs  = g - bz * (uint32_t)stPerBatch;
    const uint32_t sr  = gs / (uint32_t)scols;
    const uint32_t sc  = gs - sr * (uint32_t)scols;
    const int bm = (int)(sr * 4u + (w >> 2));
    const int bn = (int)(sc * 4u + (w & 3u));

    const int t  = threadIdx.x;
    const int wave = t >> 6, lane = t & 63;
    const int wm = (wave >> 1) * 64, wn = (wave & 1) * 64;
    const int lm = lane & 15, lq = lane >> 4;
    const int sw = lq ^ ((lm >> 1) & 3);          // read-side swizzled k-group

    const uint16_t* Ab = A  + (long)bz * bsA + (long)bm * 128 * K;
    const uint16_t* Bb = Bm + (long)bz * bsB + (long)bn * 128 * K;

    long goff[2]; int loff[2];
#pragma unroll
    for (int j = 0; j < 2; ++j) {
        const int s  = j * 256 + t;
        const int r  = s >> 2;
        const int cs = s & 3;
        const int cg = cs ^ ((r >> 1) & 3);
        goff[j] = (long)r * K + cg * 8;
        loff[j] = s * 8;
    }

    const int KI = K >> 5;

#pragma unroll
    for (int st = 0; st < 2; ++st)
#pragma unroll
        for (int j = 0; j < 2; ++j) {
            cp16(Ab + goff[j] + st * 32, SH[st] + loff[j]);
            cp16(Bb + goff[j] + st * 32, SH[st] + 4096 + loff[j]);
        }

    f32x4 acc[4][4] = {};

    int cur = 0, pf = 2;
    for (int k = 0; k < KI; ++k) {
        asm volatile("s_waitcnt vmcnt(4) lgkmcnt(0)\n\ts_barrier" ::: "memory");

        int kp = k + 2; if (kp >= KI) kp = KI - 1;
        uint16_t* dst = SH[pf];
        const long ko = (long)kp * 32;
#pragma unroll
        for (int j = 0; j < 2; ++j) {
            cp16(Ab + goff[j] + ko, dst + loff[j]);
            cp16(Bb + goff[j] + ko, dst + 4096 + loff[j]);
        }

        const uint16_t* buf = SH[cur];
        bf16x8 af[4], bfr[4];
#pragma unroll
        for (int i = 0; i < 4; ++i)
            af[i]  = *(const bf16x8*)&buf[((wm + i * 16 + lm) * 4 + sw) * 8];
#pragma unroll
        for (int i = 0; i < 4; ++i)
            bfr[i] = *(const bf16x8*)&buf[4096 + ((wn + i * 16 + lm) * 4 + sw) * 8];

#pragma unroll
        for (int i = 0; i < 4; ++i)
#pragma unroll
            for (int j = 0; j < 4; ++j)           // SWAPPED: D = C^T tile
                acc[i][j] = __builtin_amdgcn_mfma_f32_16x16x32_bf16(
                    bfr[i], af[j], acc[i][j], 0, 0, 0);

        cur = (cur == 2) ? 0 : cur + 1;
        pf  = (pf  == 2) ? 0 : pf  + 1;
    }

    // epilogue: C^T layout -> lane holds n = nb+i*16+r (r=0..3 consecutive),
    // m = mb+j*16. j-outer: each row's span completes in adjacent stores.
    const int mb = bm * 128 + wm + lm;
    const int nb = bn * 128 + wn + lq * 4;
    if (MODE == 0) {
#pragma unroll
        for (int j = 0; j < 4; ++j) {
            const int m = mb + j * 16;
#pragma unroll
            for (int i = 0; i < 4; ++i) {
                const int n = nb + i * 16;
                const uint32_t lo = (uint32_t)f2bf(acc[i][j][0] * scale) |
                                    ((uint32_t)f2bf(acc[i][j][1] * scale) << 16);
                const uint32_t hi = (uint32_t)f2bf(acc[i][j][2] * scale) |
                                    ((uint32_t)f2bf(acc[i][j][3] * scale) << 16);
                *(uint2*)&((uint16_t*)C0)[(long)bz * bsC + (long)m * ldc + n] =
                    make_uint2(lo, hi);
            }
        }
        return;
    }
    if (MODE == 7) {
        // proj: out = acc * (1/rowsum[m]) + bias  (softmax denom folded in;
        // row scalar commutes with the d-contraction, applied post-GEMM)
#pragma unroll
        for (int j = 0; j < 4; ++j) {
            const int m = mb + j * 16;
            const float inv = 1.f / bias1[m];
#pragma unroll
            for (int i = 0; i < 4; ++i) {
                const int n = nb + i * 16;
                const float4 b4 = *(const float4*)&bias0[n];
                *(float4*)&((float*)C0)[(long)m * ldc + n] = make_float4(
                    acc[i][j][0] * inv + b4.x, acc[i][j][1] * inv + b4.y,
                    acc[i][j][2] * inv + b4.z, acc[i][j][3] * inv + b4.w);
            }
        }
        return;
    }
    // MODE 3: whole block lives in one section (bn-uniform)
#pragma unroll
    for (int i = 0; i < 4; ++i) {
        const int n = nb + i * 16;
        const int sec = n >> 9, nn = n & 511;
        const float* bp = sec == 0 ? bias0 : (sec == 1 ? bias1 : bias2);
        const float4 b4 = *(const float4*)&bp[nn];
#pragma unroll
        for (int j = 0; j < 4; ++j) {
            const int m = mb + j * 16;
            if (sec < 2) {
                uint16_t* Cq = (uint16_t*)(sec == 0 ? C0 : C1);
                const uint32_t lo = (uint32_t)f2bf(acc[i][j][0] + b4.x) |
                                    ((uint32_t)f2bf(acc[i][j][1] + b4.y) << 16);
                const uint32_t hi = (uint32_t)f2bf(acc[i][j][2] + b4.z) |
                                    ((uint32_t)f2bf(acc[i][j][3] + b4.w) << 16);
                *(uint2*)&Cq[(long)m * 512 + nn] = make_uint2(lo, hi);
            } else { // V transposed: Vt[b][d][s], d = nn+r, s = m
                const int bb = m >> 11, ss = m & 2047;
                uint16_t* vt = (uint16_t*)C2 + ((long)bb * 512 + nn) * 2048 + ss;
                vt[0]        = f2bf(acc[i][j][0] + b4.x);
                vt[2048]     = f2bf(acc[i][j][1] + b4.y);
                vt[2 * 2048] = f2bf(acc[i][j][2] + b4.z);
                vt[3 * 2048] = f2bf(acc[i][j][3] + b4.w);
            }
        }
    }
}

// ---------------------------------------------------------------------------
// 256x256 / 8-wave NT GEMM, barrier-light (R10/R12 schedule -- best measured
// QK^T: 53 us, FETCH 34 MB; R13's 256x128 2/CU variant measured WORSE, 70 us,
// 1.5x staging bytes per output). One guard per iter: vmcnt(4)+lgkmcnt(0)+
// barrier; 12 ds_reads back-to-back; 4 setprio-wrapped MFMA clusters with
// compiler-placed progressive lgkm waits. MODE 4 epilogue: P = exp(acc*scale)
// bf16 + f32 row-sums atomicAdd'ed into rowsum[bz*2048+m] (pre-zeroed);
// butterfly over lane bits 4,5; lq==0 lanes issue 1 atomicAdd per (row,wave).
// j-outer store order: row's 128B span in 4 adjacent stores.
// ---------------------------------------------------------------------------
template <int MODE>
__global__ __launch_bounds__(512, 2) void gemm_nt8(
    const uint16_t* __restrict__ A, const uint16_t* __restrict__ Bm,
    void* __restrict__ C0, float* __restrict__ rowsum,
    float scale, int K, int ldc, long bsA, long bsB, long bsC,
    int scols, int stPerBatch)
{
    __shared__ __align__(16) uint16_t SH[3][16384];

    const uint32_t id  = blockIdx.x;
    const uint32_t xcd = id & 7u;
    const uint32_t p   = id >> 3;
    const uint32_t q   = p >> 4;
    const uint32_t w   = p & 15u;
    const uint32_t g   = q * 8u + xcd;
    const uint32_t bz  = g / (uint32_t)stPerBatch;
    const uint32_t gs  = g - bz * (uint32_t)stPerBatch;
    const uint32_t sr  = gs / (uint32_t)scols;
    const uint32_t sc  = gs - sr * (uint32_t)scols;
    const int bm = (int)(sr * 4u + (w >> 2));
    const int bn = (int)(sc * 4u + (w & 3u));

    const int t  = threadIdx.x;
    const int wave = t >> 6, lane = t & 63;
    const int wm2 = (wave >> 2) * 128;            // row half   (0,128)
    const int wn2 = (wave & 3) * 64;              // col quarter(0..192)
    const int lm = lane & 15, lq = lane >> 4;
    const int sw = lq ^ ((lm >> 1) & 3);

    const uint16_t* Ab = A  + (long)bz * bsA + (long)bm * 256 * K;
    const uint16_t* Bb = Bm + (long)bz * bsB + (long)bn * 256 * K;

    long goff[2]; int loff[2];
#pragma unroll
    for (int j = 0; j < 2; ++j) {
        const int s  = j * 512 + t;
        const int r  = s >> 2;
        const int cs = s & 3;
        const int cg = cs ^ ((r >> 1) & 3);
        goff[j] = (long)r * K + cg * 8;
        loff[j] = s * 8;
    }

    const int KI = K >> 5;

#pragma unroll
    for (int st = 0; st < 2; ++st)
#pragma unroll
        for (int j = 0; j < 2; ++j) {
            cp16(Ab + goff[j] + st * 32, SH[st] + loff[j]);
            cp16(Bb + goff[j] + st * 32, SH[st] + 8192 + loff[j]);
        }

    f32x4 acc[4][8] = {};

    int cur = 0, pf = 2;
    for (int k = 0; k < KI; ++k) {
        asm volatile("s_waitcnt vmcnt(4) lgkmcnt(0)\n\ts_barrier" ::: "memory");

        int kp = k + 2; if (kp >= KI) kp = KI - 1;
        uint16_t* dst = SH[pf];
        const long ko = (long)kp * 32;
#pragma unroll
        for (int j = 0; j < 2; ++j) {
            cp16(Ab + goff[j] + ko, dst + loff[j]);
            cp16(Bb + goff[j] + ko, dst + 8192 + loff[j]);
        }

        const uint16_t* buf = SH[cur];
        bf16x8 af[8], bfr[4];
#define RDA(jj) (*(const bf16x8*)&buf[((wm2 + (jj) * 16 + lm) * 4 + sw) * 8])
#define RDB(ii) (*(const bf16x8*)&buf[8192 + ((wn2 + (ii) * 16 + lm) * 4 + sw) * 8])
        bfr[0] = RDB(0); bfr[1] = RDB(1); bfr[2] = RDB(2); bfr[3] = RDB(3);
        af[0] = RDA(0); af[1] = RDA(1); af[2] = RDA(2); af[3] = RDA(3);
        af[4] = RDA(4); af[5] = RDA(5); af[6] = RDA(6); af[7] = RDA(7);
#pragma unroll
        for (int pp = 0; pp < 4; ++pp) {
            __builtin_amdgcn_s_setprio(1);
#pragma unroll
            for (int i = 0; i < 4; ++i) {
                acc[i][2 * pp]     = __builtin_amdgcn_mfma_f32_16x16x32_bf16(
                    bfr[i], af[2 * pp],     acc[i][2 * pp],     0, 0, 0);
                acc[i][2 * pp + 1] = __builtin_amdgcn_mfma_f32_16x16x32_bf16(
                    bfr[i], af[2 * pp + 1], acc[i][2 * pp + 1], 0, 0, 0);
            }
            __builtin_amdgcn_s_setprio(0);
        }
#undef RDA
#undef RDB

        cur = (cur == 2) ? 0 : cur + 1;
        pf  = (pf  == 2) ? 0 : pf  + 1;
    }

    // epilogue: C^T layout; m = row (lane&15 based), n = col (lq*4 based)
    const int mb = bm * 256 + wm2 + lm;
    const int nb = bn * 256 + wn2 + lq * 4;
#pragma unroll
    for (int j = 0; j < 8; ++j) {
        const int m = mb + j * 16;
        float rsj = 0.f;
#pragma unroll
        for (int i = 0; i < 4; ++i) {
            const int n = nb + i * 16;
            const float v0 = __expf(acc[i][j][0] * scale);
            const float v1 = __expf(acc[i][j][1] * scale);
            const float v2 = __expf(acc[i][j][2] * scale);
            const float v3 = __expf(acc[i][j][3] * scale);
            rsj += (v0 + v1) + (v2 + v3);
            const uint32_t lo = (uint32_t)f2bf(v0) | ((uint32_t)f2bf(v1) << 16);
            const uint32_t hi = (uint32_t)f2bf(v2) | ((uint32_t)f2bf(v3) << 16);
            *(uint2*)&((uint16_t*)C0)[(long)bz * bsC + (long)m * ldc + n] =
                make_uint2(lo, hi);
        }
        // sum this wave's 64-col slice of row m across lq (lane bits 4,5)
        rsj += __shfl_xor(rsj, 16);
        rsj += __shfl_xor(rsj, 32);
        if (lq == 0)
            atomicAdd(&rowsum[(long)bz * 2048 + m], rsj);
    }
}

// x + pos_table -> bf16, 8 elems/thread, exact grid (4096 blocks)
__global__ __launch_bounds__(256) void prep_x(const float* __restrict__ x,
                                              const float* __restrict__ pos,
                                              uint16_t* __restrict__ xb)
{
    const long i8 = ((long)blockIdx.x * 256 + threadIdx.x) * 8;
    const long p8 = i8 & ((1l << 20) - 1);   // S*D = 2^20
    const float4* xv = (const float4*)(x + i8);
    const float4* pv = (const float4*)(pos + p8);
    const float4 a0 = xv[0], a1 = xv[1];
    const float4 b0 = pv[0], b1 = pv[1];
    uint16_t o[8];
    o[0] = f2bf(a0.x + b0.x); o[1] = f2bf(a0.y + b0.y);
    o[2] = f2bf(a0.z + b0.z); o[3] = f2bf(a0.w + b0.w);
    o[4] = f2bf(a1.x + b1.x); o[5] = f2bf(a1.y + b1.y);
    o[6] = f2bf(a1.z + b1.z); o[7] = f2bf(a1.w + b1.w);
    *(uint4*)(xb + i8) = *(uint4*)o;
}

// Wq,Wk,Wv -> stacked wqkv[1536,512] bf16; Wd -> wd bf16. 512 blocks exact.
__global__ __launch_bounds__(256) void prep_w(
    const float* __restrict__ Wq, const float* __restrict__ Wk,
    const float* __restrict__ Wv, const float* __restrict__ Wd,
    uint16_t* __restrict__ wqkv, uint16_t* __restrict__ wd)
{
    const long f = ((long)blockIdx.x * 256 + threadIdx.x) * 8;
    const int  w = (int)(f >> 18);          // 262144 elems per weight
    const long off = f & 262143;
    const float* src = (w == 0) ? Wq : (w == 1) ? Wk : (w == 2) ? Wv : Wd;
    uint16_t* dst = (w < 3) ? (wqkv + (long)w * 262144 + off) : (wd + off);
    const float4* s4 = (const float4*)(src + off);
    const float4 a = s4[0], b = s4[1];
    uint16_t o[8];
    o[0] = f2bf(a.x); o[1] = f2bf(a.y); o[2] = f2bf(a.z); o[3] = f2bf(a.w);
    o[4] = f2bf(b.x); o[5] = f2bf(b.y); o[6] = f2bf(b.z); o[7] = f2bf(b.w);
    *(uint4*)dst = *(uint4*)o;
}

extern "C" void kernel_launch(void* const* d_in, const int* in_sizes, int n_in,
                              void* d_out, int out_size, void* d_ws, size_t ws_size,
                              hipStream_t stream)
{
    const float* x   = (const float*)d_in[0];
    const float* pos = (const float*)d_in[1];
    const float* Wq  = (const float*)d_in[2];
    const float* bq  = (const float*)d_in[3];
    const float* Wk  = (const float*)d_in[4];
    const float* bk  = (const float*)d_in[5];
    const float* Wv  = (const float*)d_in[6];
    const float* bv  = (const float*)d_in[7];
    const float* Wd  = (const float*)d_in[8];
    const float* bd  = (const float*)d_in[9];
    float* out = (float*)d_out;

    // workspace layout (bytes), total 153,092,096
    char* ws = (char*)d_ws;
    uint16_t* xb   = (uint16_t*)(ws);                 // 16,777,216  [16384,512]
    uint16_t* wqkv = (uint16_t*)(ws + 16777216);      //  1,572,864  [1536,512]
    uint16_t* wd   = (uint16_t*)(ws + 18350080);      //    524,288  [512,512]
    uint16_t* Qb   = (uint16_t*)(ws + 18874368);      // 16,777,216  [16384,512]
    uint16_t* Kb   = (uint16_t*)(ws + 35651584);      // 16,777,216  [16384,512]
    uint16_t* Vt   = (uint16_t*)(ws + 52428800);      // 16,777,216  [8,512,2048]
    uint16_t* Pb   = (uint16_t*)(ws + 69206016);      // 67,108,864  [8,2048,2048]
    uint16_t* yb   = (uint16_t*)(ws + 136314880);     // 16,777,216  [16384,512]
    // rowsum[16384] f32 (64 KB) reuses xb's region -- xb is dead after QKV.
    float* rowsum = (float*)ws;

    prep_x<<<4096, 256, 0, stream>>>(x, pos, xb);
    prep_w<<<512, 256, 0, stream>>>(Wq, Wk, Wv, Wd, wqkv, wd);

    // Q|K|Vt = xb @ wqkv^T (+bias):  M=16384, N=1536, K=512
    gemm_nt<3><<<1536, 256, 0, stream>>>(
        xb, wqkv, Qb, Kb, Vt, bq, bk, bv, 1.0f, 512, 512, 0, 0, 0, 3, 96);

    // zero softmax-denominator accumulator (xb region now dead)
    hipMemsetAsync(rowsum, 0, 16384 * sizeof(float), stream);

    // P[b] = exp((Q[b] @ K[b]^T) * scale), rowsum += per-row sums (atomics)
    // 8 x [2048,2048], K=512 -- 256^2 barrier-light kernel (R12 best: 53 us):
    // per batch gm=8, gn=8 -> scols=2, stPerBatch=4, blocks=512, 512 thr
    gemm_nt8<4><<<512, 512, 0, stream>>>(
        Qb, Kb, Pb, rowsum, QK_SCALE, 512, 2048, (long)2048 * 512,
        (long)2048 * 512, (long)2048 * 2048, 2, 4);

    // y'[b] = P[b] @ Vt[b]^T (UN-normalized; denom applied in proj):
    // 8 x [2048,512], K=2048; 128^2 tile: gm=16, gn=4 -> scols=1, spb=4
    gemm_nt<0><<<512, 256, 0, stream>>>(
        Pb, Vt, yb, nullptr, nullptr, nullptr, nullptr, nullptr,
        1.0f, 2048, 512, (long)2048 * 2048, (long)512 * 2048,
        (long)2048 * 512, 1, 4);

    // out = (y'/rowsum) @ wd^T + bd = (y' @ wd^T) * inv[m] + bd
    // M=16384, N=512, K=512, fp32 out; gm=128, gn=4 -> scols=1, spb=32
    gemm_nt<7><<<512, 256, 0, stream>>>(
        yb, wd, out, nullptr, nullptr, bd, rowsum, nullptr,
        1.0f, 512, 512, 0, 0, 0, 1, 32);
}